// Round 11
// baseline (1148.056 us; speedup 1.0000x reference)
//
#include <hip/hip_runtime.h>

// RGCN: N=50000, E=600000, D=128, R=200, NB=4, ARD=32, L=2, G=50, NS=2000
// R15: revert R14's two hoists (4th allocator-spill datapoint: under
//      launch_bounds(512,8) hipcc pins k_attn at 32 VGPR and spills ANY extra
//      live state -> pre-barrier payload hoisting is dead on this kernel).
//      Forward moves attack REQUEST COUNT, not latency (no new live regs):
//      (a) k_attn: 2 edge-batches per block (256 edges, grid 2344, unroll-1
//          loop) -> QW LDS-restage halved (9.6M -> 4.8M L2 requests).
//      (b) epk[p] = int4{src,tgt,rel,eid} packed by k_fill: 4 dependent scalar
//          idx loads -> one 16B load (and k_fill scatter 4x4B -> 1x16B).
//      k_reduce = R13 body. Arithmetic bit-identical to R13 (830us).
//   per layer l:
//     k_bigwT  : BigW^T split -> BThi/BTlo [896][128] bf16
//     k_qw     : A_w[:,256:320] split -> QWhi/QWlo [128][64] bf16
//     k_splitX : X -> Xhi/Xlo bf16x2 (NP=50048 padded)
//     k_mgemm  : 3-pass bf16x2 MFMA -> xw16 (Nx512 fp16), pstT (Nx256 fp16,
//                permuted), curr -> feats[:, l*128:+128] fp32
//     k_attn   : 256 CSR edges/block (2 batches), MFMA q-GEMM + MLP -> acf[p]
//     k_reduce : wave-per-tgt CSR reduction over fp16 xw, fp32 accum
// All accumulation fp32. ws ~176 MB.

#define NN 50000
#define NP 50048   // 391 * 128
#define EE 600000
#define DD 128
#define RR 200
#define NBASIS 4
#define LL 2
#define GG 50
#define NSRC 2000
#define GCH 8
#define SCANB 196  // ceil(NN/256)

typedef __attribute__((ext_vector_type(8))) short short8v;
typedef __attribute__((ext_vector_type(4))) float float4v;
typedef __attribute__((ext_vector_type(8))) _Float16 half8v;
typedef __attribute__((ext_vector_type(4))) _Float16 half4v;

__device__ __forceinline__ void f4a(const float4 v, float* a) {
  a[0] = v.x; a[1] = v.y; a[2] = v.z; a[3] = v.w;
}

__device__ __forceinline__ unsigned short f2bf(float v) {  // RNE bf16
  unsigned u = __float_as_uint(v);
  unsigned r = u + 0x7FFFu + ((u >> 16) & 1u);
  return (unsigned short)(r >> 16);
}
__device__ __forceinline__ float bf2f(unsigned short h) {
  return __uint_as_float(((unsigned)h) << 16);
}

// split 8 floats into hi/lo bf16 vectors
__device__ __forceinline__ void split8s(const float4 a, const float4 b,
                                        short8v* hi, short8v* lo) {
  float f[8];
  f4a(a, f); f4a(b, f + 4);
  short8v h, l;
#pragma unroll
  for (int j = 0; j < 8; ++j) {
    unsigned short hh = f2bf(f[j]);
    h[j] = (short)hh;
    l[j] = (short)f2bf(f[j] - bf2f(hh));
  }
  *hi = h; *lo = l;
}

// ---------------- BigW^T assembly + bf16x2 split: BT*[c*128 + i] ----------------
__global__ __launch_bounds__(256) void k_bigwT(const float* __restrict__ weights,
                                               const float* __restrict__ A_w,
                                               const float* __restrict__ self_loops,
                                               unsigned short* __restrict__ BThi,
                                               unsigned short* __restrict__ BTlo, int l) {
  int id = blockIdx.x * 256 + threadIdx.x;
  if (id >= 128 * 896) return;
  int i = id / 896, c = id % 896;  // i = K index, c = output col
  float v;
  if (c < 512) {            // xw: col b*128+o = weights[l][b][i][o]
    int b = c >> 7, o = c & 127;
    v = weights[((l * NBASIS + b) * DD + i) * DD + o];
  } else if (c < 640) {     // psrc
    int j = c - 512;
    v = A_w[(l * DD + j) * 320 + i];
  } else if (c < 768) {     // ptgt
    int j = c - 640;
    v = A_w[(l * DD + j) * 320 + 128 + i];
  } else {                  // curr
    int o = c - 768;
    v = self_loops[(l * DD + i) * DD + o];
  }
  unsigned short hi = f2bf(v);
  unsigned short lo = f2bf(v - bf2f(hi));
  BThi[c * 128 + i] = hi;
  BTlo[c * 128 + i] = lo;
}

// ---------------- q-GEMM weights: QW[j][k] = A_w[l][j][256+k], hi/lo bf16 ----------------
__global__ __launch_bounds__(256) void k_qw(const float* __restrict__ A_w,
                                            unsigned short* __restrict__ QWhi,
                                            unsigned short* __restrict__ QWlo, int l) {
  int id = blockIdx.x * 256 + threadIdx.x;
  if (id >= 128 * 64) return;
  int j = id >> 6, k = id & 63;
  float v = A_w[(l * DD + j) * 320 + 256 + k];
  unsigned short hi = f2bf(v);
  QWhi[id] = hi;
  QWlo[id] = f2bf(v - bf2f(hi));
}

// ---------------- X bf16x2 split (padded to NP rows) ----------------
__global__ __launch_bounds__(256) void k_splitX(const float* __restrict__ X, int xs,
                                                unsigned short* __restrict__ Xhi,
                                                unsigned short* __restrict__ Xlo) {
  int id = blockIdx.x * 256 + threadIdx.x;
  if (id >= NP * 128) return;
  int n = id >> 7, k = id & 127;
  float v = (n < NN) ? X[(size_t)n * xs + k] : 0.0f;
  unsigned short hi = f2bf(v);
  unsigned short lo = f2bf(v - bf2f(hi));
  Xhi[id] = hi;
  Xlo[id] = lo;
}

// ---------------- MFMA node GEMM: block 128m x 128n, wave 32m x 128n ----------------
// LDS: K-loop stages B (hi+lo) at stride 56 halves (2-way banks, 16B aligned);
// epilogue reuses LDS for C transpose -> coalesced half8/float4 row stores.
// pst (cb 4,5) written PERMUTED: col' = (lm>>2)*32 + nt*4 + (lm&3) so k_attn's
// per-lane ps/pt reads are contiguous 64B runs.
__global__ __launch_bounds__(256) void k_mgemm(const unsigned short* __restrict__ Xhi,
                                               const unsigned short* __restrict__ Xlo,
                                               const unsigned short* __restrict__ BThi,
                                               const unsigned short* __restrict__ BTlo,
                                               _Float16* __restrict__ xw16,
                                               _Float16* __restrict__ pst16,
                                               float* __restrict__ currdst) {
  __shared__ __align__(16) char smem[34816];
  unsigned short* sBhi = (unsigned short*)smem;        // [128][56] halves
  unsigned short* sBlo = sBhi + 128 * 56;
  _Float16* sC = (_Float16*)smem;                      // [128][136] halves (34816 B)
  float* sCf = (float*)smem;                           // [64][132] floats (33792 B)

  const int t = threadIdx.x;
  const int wv = t >> 6, lane = t & 63;
  const int lm = lane & 15, qd = lane >> 4;
  const int m0 = blockIdx.x * 128;
  const int cb = blockIdx.y;           // 0..6
  const int n0 = cb * 128;
  const int mw = m0 + wv * 32;         // wave's 32-row strip

  float4v acc[2][8];
#pragma unroll
  for (int mi = 0; mi < 2; ++mi)
#pragma unroll
    for (int nt = 0; nt < 8; ++nt) acc[mi][nt] = (float4v)(0.0f);

  const int sn = (t >> 2);             // staging row 0..63 (+64 on rep 1)
  const int skq = (t & 3) * 8;         // staging k-offset (halves)

  for (int kc = 0; kc < 128; kc += 32) {
    // stage B tile (128n x 32k, hi+lo) -> LDS
    short8v vh0 = *(const short8v*)(BThi + (size_t)(n0 + sn) * 128 + kc + skq);
    short8v vl0 = *(const short8v*)(BTlo + (size_t)(n0 + sn) * 128 + kc + skq);
    short8v vh1 = *(const short8v*)(BThi + (size_t)(n0 + 64 + sn) * 128 + kc + skq);
    short8v vl1 = *(const short8v*)(BTlo + (size_t)(n0 + 64 + sn) * 128 + kc + skq);
    if (kc) __syncthreads();           // prev tile's reads complete
    *(short8v*)&sBhi[sn * 56 + skq] = vh0;
    *(short8v*)&sBlo[sn * 56 + skq] = vl0;
    *(short8v*)&sBhi[(64 + sn) * 56 + skq] = vh1;
    *(short8v*)&sBlo[(64 + sn) * 56 + skq] = vl1;
    __syncthreads();
    // A fragments direct from global (L3-resident)
    short8v ah[2], al[2];
#pragma unroll
    for (int mi = 0; mi < 2; ++mi) {
      ah[mi] = *(const short8v*)(Xhi + (size_t)(mw + mi * 16 + lm) * 128 + kc + qd * 8);
      al[mi] = *(const short8v*)(Xlo + (size_t)(mw + mi * 16 + lm) * 128 + kc + qd * 8);
    }
#pragma unroll
    for (int nt = 0; nt < 8; ++nt) {
      short8v bh = *(const short8v*)&sBhi[(nt * 16 + lm) * 56 + qd * 8];
      short8v bl = *(const short8v*)&sBlo[(nt * 16 + lm) * 56 + qd * 8];
#pragma unroll
      for (int mi = 0; mi < 2; ++mi) {
        acc[mi][nt] = __builtin_amdgcn_mfma_f32_16x16x32_bf16(ah[mi], bh, acc[mi][nt], 0, 0, 0);
        acc[mi][nt] = __builtin_amdgcn_mfma_f32_16x16x32_bf16(ah[mi], bl, acc[mi][nt], 0, 0, 0);
        acc[mi][nt] = __builtin_amdgcn_mfma_f32_16x16x32_bf16(al[mi], bh, acc[mi][nt], 0, 0, 0);
      }
    }
  }

  // epilogue: C/D layout col = lane&15, row = qd*4 + reg  [m89/m91]
  if (cb < 6) {                        // fp16 tables, LDS transpose -> half8 row stores
    _Float16* dst16; int stride, off;
    if (cb < 4) { dst16 = xw16;  stride = 512; off = cb * 128; }
    else        { dst16 = pst16; stride = 256; off = (cb - 4) * 128; }
    __syncthreads();
#pragma unroll
    for (int mi = 0; mi < 2; ++mi)
#pragma unroll
      for (int nt = 0; nt < 8; ++nt)
#pragma unroll
        for (int r = 0; r < 4; ++r) {
          int col = (cb < 4) ? (nt * 16 + lm) : ((lm >> 2) * 32 + nt * 4 + (lm & 3));
          sC[(wv * 32 + mi * 16 + qd * 4 + r) * 136 + col] = (_Float16)acc[mi][nt][r];
        }
    __syncthreads();
#pragma unroll
    for (int rep = 0; rep < 8; ++rep) {
      int idx = rep * 256 + t;
      int row = idx >> 4, li = idx & 15;
      int m = m0 + row;
      if (m < NN)
        *(half8v*)&dst16[(size_t)m * stride + off + li * 8] =
            *(const half8v*)&sC[row * 136 + li * 8];
    }
  } else {                             // curr -> fp32 feats, two 64-row passes
#pragma unroll
    for (int pass = 0; pass < 2; ++pass) {
      __syncthreads();
      if ((wv >> 1) == pass) {
        int rbase = (wv & 1) * 32;
#pragma unroll
        for (int mi = 0; mi < 2; ++mi)
#pragma unroll
          for (int nt = 0; nt < 8; ++nt)
#pragma unroll
            for (int r = 0; r < 4; ++r)
              sCf[(rbase + mi * 16 + qd * 4 + r) * 132 + nt * 16 + lm] = acc[mi][nt][r];
      }
      __syncthreads();
#pragma unroll
      for (int rep = 0; rep < 8; ++rep) {
        int idx = rep * 256 + t;
        int lr = idx >> 5, li = idx & 31;
        int m = m0 + pass * 64 + lr;
        if (m < NN)
          *(float4*)&currdst[(size_t)m * 256 + li * 4] =
              *(const float4*)&sCf[lr * 132 + li * 4];
      }
    }
  }
}

// ---------------- Attention: 512 threads, 256 CSR edges/block (2 batches) ----------------
// Swapped MFMA: C[row=j][col=edge]. Lane (qd,lm) of wave wv handles edge
// p = blk*256 + b*128 + wv*16 + lm, holding j = nt*16 + qd*4 + r.
// QW staged once per block (swizzled LDS); unroll-1 batch loop keeps the
// per-iteration live set identical to R13's body (allocator pins 32 VGPR).
// ps/pt stay inside the group loop (R14 hoist spilled — allocator won't grow).
__global__ __launch_bounds__(512, 8) void k_attn(
    const int4* __restrict__ epk,
    const float* __restrict__ re, const float* __restrict__ tr,
    const unsigned short* __restrict__ QWhi, const unsigned short* __restrict__ QWlo,
    const float* __restrict__ A_b, const float* __restrict__ B_w,
    const float* __restrict__ B_b, const float* __restrict__ w_comps,
    const _Float16* __restrict__ pst16, float* __restrict__ acf, int l) {
  __shared__ __align__(16) unsigned short sQW[2 * 8192];   // hi | lo, 32768 B
  const int t = threadIdx.x;

  // stage QW -> LDS, XOR-swizzled: 16B chunk idx at byte idx*16 ^ ((idx>>3&7)<<4)
#pragma unroll
  for (int r = 0; r < 2; ++r) {
    int idx = r * 512 + t;                               // 0..1023
    int ad = (idx * 16) ^ (((idx >> 3) & 7) << 4);
    *(short8v*)((char*)sQW + ad) = *(const short8v*)(QWhi + idx * 8);
    *(short8v*)((char*)sQW + 16384 + ad) = *(const short8v*)(QWlo + idx * 8);
  }

  const int wv = t >> 6, lane = t & 63;
  const int lm = lane & 15, qd = lane >> 4;
  const int sw = (lm & 7) << 4;
  const float Bb = B_b[l];

#pragma unroll 1
  for (int b = 0; b < 2; ++b) {
    const int p = blockIdx.x * 256 + b * 128 + wv * 16 + lm;
    const int pc = min(p, EE - 1);                // tail clamp (loads only)
    const int4 ev = epk[pc];                      // {src, tgt, rel, eid}
    const int src = ev.x, tgt = ev.y, rel_ = ev.z, eid = ev.w;

    // E fragment: ecat[edge][k = kc + qd*8 .. +8), kc=0 -> re, kc=32 -> tr
    float4 r0 = *(const float4*)&re[(size_t)eid * 32 + qd * 8];
    float4 r1 = *(const float4*)&re[(size_t)eid * 32 + qd * 8 + 4];
    float4 t0 = *(const float4*)&tr[(size_t)eid * 32 + qd * 8];
    float4 t1 = *(const float4*)&tr[(size_t)eid * 32 + qd * 8 + 4];
    short8v eh0, el0, eh1, el1;
    split8s(r0, r1, &eh0, &el0);
    split8s(t0, t1, &eh1, &el1);

    if (b == 0) __syncthreads();   // QW staged; batch-0 gathers overlap the stage

    const _Float16* psp = pst16 + (size_t)src * 256 + qd * 32;
    const _Float16* ptp = pst16 + (size_t)tgt * 256 + 128 + qd * 32;
    float part = 0.0f;
#pragma unroll
    for (int g = 0; g < 4; ++g) {
      // group covers nt = 2g (ps[0..3]) and 2g+1 (ps[4..7])
      half8v ps = *(const half8v*)(psp + g * 8);
      half8v pt = *(const half8v*)(ptp + g * 8);
      float4v aa[2];
      aa[0] = (float4v)(0.0f);
      aa[1] = (float4v)(0.0f);
#pragma unroll
      for (int h = 0; h < 2; ++h) {
        const int nt = 2 * g + h;
        const int rowb = (nt * 16 + lm) * 128 + qd * 16; // byte offset in hi half
        short8v wh0 = *(const short8v*)((char*)sQW + (rowb ^ sw));
        short8v wl0 = *(const short8v*)((char*)sQW + 16384 + (rowb ^ sw));
        // kc = 0 (re half), 3-pass hi/lo
        aa[h] = __builtin_amdgcn_mfma_f32_16x16x32_bf16(wh0, eh0, aa[h], 0, 0, 0);
        aa[h] = __builtin_amdgcn_mfma_f32_16x16x32_bf16(wl0, eh0, aa[h], 0, 0, 0);
        aa[h] = __builtin_amdgcn_mfma_f32_16x16x32_bf16(wh0, el0, aa[h], 0, 0, 0);
        short8v wh1 = *(const short8v*)((char*)sQW + ((rowb + 64) ^ sw));
        short8v wl1 = *(const short8v*)((char*)sQW + 16384 + ((rowb + 64) ^ sw));
        // kc = 32 (tr half)
        aa[h] = __builtin_amdgcn_mfma_f32_16x16x32_bf16(wh1, eh1, aa[h], 0, 0, 0);
        aa[h] = __builtin_amdgcn_mfma_f32_16x16x32_bf16(wl1, eh1, aa[h], 0, 0, 0);
        aa[h] = __builtin_amdgcn_mfma_f32_16x16x32_bf16(wh1, el1, aa[h], 0, 0, 0);
      }
      // MLP partial for this group (same per-nt term order as R13)
#pragma unroll
      for (int h = 0; h < 2; ++h) {
        const int nt = 2 * g + h;
        float4 ab = *(const float4*)&A_b[l * DD + nt * 16 + qd * 4];
        float4 bw = *(const float4*)&B_w[l * DD + nt * 16 + qd * 4];
        float abv[4], bwv[4];
        f4a(ab, abv); f4a(bw, bwv);
#pragma unroll
        for (int r = 0; r < 4; ++r) {
          float psf = (float)ps[h * 4 + r];
          float ptf = (float)pt[h * 4 + r];
          float hh = fmaxf(psf + ptf + aa[h][r] + abv[r], 0.0f);
          part += hh * bwv[r];
        }
      }
    }
    part += __shfl_xor(part, 16, 64);
    part += __shfl_xor(part, 32, 64);
    if (qd == 0 && p < EE) {
      const float a = 1.0f / (1.0f + expf(-(part + Bb)));
      const float4 cf = *(const float4*)&w_comps[(l * RR + rel_) * 4];
      *(float4*)&acf[(size_t)p * 4] = make_float4(a * cf.x, a * cf.y, a * cf.z, a * cf.w);
    }
  }
}

// ---------------- CSR build ----------------
__global__ __launch_bounds__(256) void k_zero_i(int* __restrict__ p, int n) {
  int id = blockIdx.x * 256 + threadIdx.x;
  if (id < n) p[id] = 0;
}
__global__ __launch_bounds__(256) void k_hist(const int* __restrict__ e_tgt,
                                              int* __restrict__ deg) {
  int e = blockIdx.x * 256 + threadIdx.x;
  if (e < EE) atomicAdd(&deg[e_tgt[e]], 1);
}

// 3-phase multi-block exclusive scan of deg -> rowptr/cursor
__global__ __launch_bounds__(256) void k_scan1(const int* __restrict__ deg,
                                               int* __restrict__ bsum) {
  __shared__ int red[4];
  const int t = threadIdx.x;
  int i = blockIdx.x * 256 + t;
  int v = (i < NN) ? deg[i] : 0;
#pragma unroll
  for (int m = 1; m < 64; m <<= 1) v += __shfl_xor(v, m, 64);
  if ((t & 63) == 0) red[t >> 6] = v;
  __syncthreads();
  if (t == 0) bsum[blockIdx.x] = red[0] + red[1] + red[2] + red[3];
}
__global__ __launch_bounds__(256) void k_scan2(const int* __restrict__ bsum,
                                               int* __restrict__ boff) {
  __shared__ int s[256];
  const int t = threadIdx.x;
  int v = (t < SCANB) ? bsum[t] : 0;
  s[t] = v;
  __syncthreads();
  for (int off = 1; off < 256; off <<= 1) {
    int u = (t >= off) ? s[t - off] : 0;
    __syncthreads();
    s[t] += u;
    __syncthreads();
  }
  if (t < SCANB) boff[t] = s[t] - v;   // exclusive
}
__global__ __launch_bounds__(256) void k_scan3(const int* __restrict__ deg,
                                               const int* __restrict__ boff,
                                               int* __restrict__ rowptr,
                                               int* __restrict__ cursor) {
  __shared__ int s[256];
  const int t = threadIdx.x;
  const int i = blockIdx.x * 256 + t;
  int v = (i < NN) ? deg[i] : 0;
  s[t] = v;
  __syncthreads();
  for (int off = 1; off < 256; off <<= 1) {
    int u = (t >= off) ? s[t - off] : 0;
    __syncthreads();
    s[t] += u;
    __syncthreads();
  }
  if (i < NN) {
    int ex = boff[blockIdx.x] + s[t] - v;
    rowptr[i] = ex;
    cursor[i] = ex;
  }
  if (i == NN - 1) rowptr[NN] = EE;
}

// fill: CSR-order srcs + packed edge record epk (layer-invariant)
__global__ __launch_bounds__(256) void k_fill(const int* __restrict__ e_tgt,
                                              const int* __restrict__ e_src,
                                              const int* __restrict__ rel,
                                              int* __restrict__ cursor,
                                              int* __restrict__ srcs,
                                              int4* __restrict__ epk) {
  int e = blockIdx.x * 256 + threadIdx.x;
  if (e < EE) {
    int tg = e_tgt[e];
    int sr = e_src[e];
    int p = atomicAdd(&cursor[tg], 1);
    srcs[p] = sr;
    epk[p] = make_int4(sr, tg, rel[e], e);
  }
}

// ---------------- CSR segmented reduction: one wave per tgt node ----------------
__global__ __launch_bounds__(256) void k_reduce(
    const int* __restrict__ rowptr, const int* __restrict__ srcs,
    const float* __restrict__ acf, const _Float16* __restrict__ xw16,
    float* __restrict__ feats, int l) {
  const int t = threadIdx.x;
  const int wave = t >> 6, lane = t & 63;
  const int n = blockIdx.x * 4 + wave;
  if (n >= NN) return;
  const int b = lane >> 4, li = lane & 15;
  float s[8] = {0, 0, 0, 0, 0, 0, 0, 0};
  const int lo = rowptr[n], hi = rowptr[n + 1];
  int snext = 0; float cnext = 0.0f;
  if (lo < hi) { snext = srcs[lo]; cnext = acf[lo * 4 + b]; }
  for (int i = lo; i < hi; ++i) {
    const int src = snext; const float cb_ = cnext;
    if (i + 1 < hi) { snext = srcs[i + 1]; cnext = acf[(i + 1) * 4 + b]; }
    half8v x = *(const half8v*)&xw16[(size_t)src * 512 + b * 128 + li * 8];
#pragma unroll
    for (int j = 0; j < 8; ++j) s[j] += cb_ * (float)x[j];
  }
#pragma unroll
  for (int j = 0; j < 8; ++j) {
    s[j] += __shfl_xor(s[j], 16, 64);
    s[j] += __shfl_xor(s[j], 32, 64);
  }
  if (lane < 16) {
    float* fp = &feats[(size_t)n * 256 + l * 128 + lane * 8];
    float4 c0 = *(const float4*)fp;
    float4 c1 = *(const float4*)(fp + 4);
    float4 o0 = make_float4(fmaxf(s[0] + c0.x, 0.f), fmaxf(s[1] + c0.y, 0.f),
                            fmaxf(s[2] + c0.z, 0.f), fmaxf(s[3] + c0.w, 0.f));
    float4 o1 = make_float4(fmaxf(s[4] + c1.x, 0.f), fmaxf(s[5] + c1.y, 0.f),
                            fmaxf(s[6] + c1.z, 0.f), fmaxf(s[7] + c1.w, 0.f));
    *(float4*)fp = o0;
    *(float4*)(fp + 4) = o1;
  }
}

// ---------------- readout ----------------
__global__ __launch_bounds__(256) void k_gather(const int* __restrict__ srcn,
                                                const int* __restrict__ tgtn,
                                                const float* __restrict__ feats,
                                                float* __restrict__ out) {
  int id = blockIdx.x * 256 + threadIdx.x;
  if (id >= 2 * NSRC * 256) return;
  int half = id / (NSRC * 256);
  int rem = id % (NSRC * 256);
  int s = rem >> 8, c = rem & 255;
  int n = half ? tgtn[s] : srcn[s];
  int base = GG * 256 + half * NSRC * 256;
  out[base + s * 256 + c] = feats[n * 256 + c];
}

__global__ __launch_bounds__(256) void k_zero(float* __restrict__ p, int n) {
  int id = blockIdx.x * 256 + threadIdx.x;
  if (id < n) p[id] = 0.0f;
}

__global__ __launch_bounds__(256) void k_graphsum(const int* __restrict__ gid,
                                                  const float* __restrict__ feats,
                                                  float* __restrict__ gsum,
                                                  float* __restrict__ gcnt) {
  const int g = blockIdx.x / GCH, ch = blockIdx.x % GCH;
  __shared__ int sb[2];
  if (threadIdx.x == 0) {
    int lo = 0, hi = NN;
    while (lo < hi) { int m = (lo + hi) >> 1; if (gid[m] < g) lo = m + 1; else hi = m; }
    sb[0] = lo;
    lo = 0; hi = NN;
    while (lo < hi) { int m = (lo + hi) >> 1; if (gid[m] < g + 1) lo = m + 1; else hi = m; }
    sb[1] = lo;
  }
  __syncthreads();
  const int lo = sb[0], hi = sb[1];
  if (ch == 0 && threadIdx.x == 0) gcnt[g] = (float)(hi - lo);
  const int cnt = hi - lo;
  const int per = (cnt + GCH - 1) / GCH;
  const int nlo = lo + ch * per, nhi = min(nlo + per, hi);
  float s = 0.0f;
  const int c = threadIdx.x;
  for (int n = nlo; n < nhi; ++n) s += feats[n * 256 + c];
  atomicAdd(&gsum[g * 256 + c], s);
}

__global__ __launch_bounds__(256) void k_graphdiv(const float* __restrict__ gsum,
                                                  const float* __restrict__ gcnt,
                                                  float* __restrict__ out) {
  int id = blockIdx.x * 256 + threadIdx.x;
  if (id >= GG * 256) return;
  out[id] = gsum[id] / gcnt[id >> 8];
}

extern "C" void kernel_launch(void* const* d_in, const int* in_sizes, int n_in,
                              void* d_out, int out_size, void* d_ws, size_t ws_size,
                              hipStream_t stream) {
  const float* node_feat  = (const float*)d_in[0];
  const int*   edge       = (const int*)d_in[1];
  const int*   rel        = (const int*)d_in[2];
  const float* re         = (const float*)d_in[3];
  const float* tr         = (const float*)d_in[4];
  const int*   srcn       = (const int*)d_in[5];
  const int*   tgtn       = (const int*)d_in[6];
  const int*   gid        = (const int*)d_in[7];
  const float* weights    = (const float*)d_in[8];
  const float* w_comps    = (const float*)d_in[9];
  const float* self_loops = (const float*)d_in[10];
  const float* A_w        = (const float*)d_in[11];
  const float* A_b        = (const float*)d_in[12];
  const float* B_w        = (const float*)d_in[13];
  const float* B_b        = (const float*)d_in[14];
  float* out = (float*)d_out;

  float* ws    = (float*)d_ws;
  float* feats = ws;                            // N*256 f32
  float* gsum  = feats + (size_t)NN * 256;      // GG*256
  float* gcnt  = gsum + GG * 256;               // 64
  float* acf   = gcnt + 64;                     // E*4
  _Float16* xw16  = (_Float16*)(acf + (size_t)EE * 4);  // N*512 fp16
  _Float16* pst16 = xw16 + (size_t)NN * 512;            // N*256 fp16 (permuted)
  unsigned short* Xhi  = (unsigned short*)(pst16 + (size_t)NN * 256);  // NP*128
  unsigned short* Xlo  = Xhi + (size_t)NP * 128;
  unsigned short* BThi = Xlo + (size_t)NP * 128;        // 896*128
  unsigned short* BTlo = BThi + 896 * 128;
  int4* epk   = (int4*)(BTlo + 896 * 128);      // E (16B-aligned here)
  int* deg    = (int*)(epk + EE);               // N
  int* rowptr = deg + NN;                       // N+1
  int* cursor = rowptr + NN + 1;                // N
  int* srcs   = cursor + NN;                    // E
  unsigned short* QWhi = (unsigned short*)(srcs + EE);  // 128*64
  unsigned short* QWlo = QWhi + 128 * 64;
  int* bsum   = (int*)(QWlo + 128 * 64);        // SCANB
  int* boff   = bsum + 256;                     // SCANB
  // total ws ~176 MB

  const int* e_src = edge;
  const int* e_tgt = edge + EE;

  // CSR by tgt (layer-invariant)
  k_zero_i<<<(NN + 255) / 256, 256, 0, stream>>>(deg, NN);
  k_hist<<<(EE + 255) / 256, 256, 0, stream>>>(e_tgt, deg);
  k_scan1<<<SCANB, 256, 0, stream>>>(deg, bsum);
  k_scan2<<<1, 256, 0, stream>>>(bsum, boff);
  k_scan3<<<SCANB, 256, 0, stream>>>(deg, boff, rowptr, cursor);
  k_fill<<<(EE + 255) / 256, 256, 0, stream>>>(e_tgt, e_src, rel, cursor,
                                               srcs, epk);

  for (int l = 0; l < LL; ++l) {
    const float* X = (l == 0) ? node_feat : feats;  // layer1 input = feats[:, 0:128]
    int xs = (l == 0) ? 128 : 256;
    k_bigwT<<<(128 * 896 + 255) / 256, 256, 0, stream>>>(weights, A_w, self_loops,
                                                         BThi, BTlo, l);
    k_qw<<<(128 * 64 + 255) / 256, 256, 0, stream>>>(A_w, QWhi, QWlo, l);
    k_splitX<<<(NP * 128 + 255) / 256, 256, 0, stream>>>(X, xs, Xhi, Xlo);
    dim3 g1(NP / 128, 7);
    k_mgemm<<<g1, 256, 0, stream>>>(Xhi, Xlo, BThi, BTlo, xw16, pst16, feats + l * 128);
    k_attn<<<(EE + 255) / 256, 512, 0, stream>>>(epk, re, tr,
                                                 QWhi, QWlo, A_b, B_w, B_b, w_comps,
                                                 pst16, acf, l);
    k_reduce<<<(NN + 3) / 4, 256, 0, stream>>>(rowptr, srcs, acf, xw16, feats, l);
  }
  k_gather<<<(2 * NSRC * 256 + 255) / 256, 256, 0, stream>>>(srcn, tgtn, feats, out);
  k_zero<<<(GG * 256 + 64 + 255) / 256, 256, 0, stream>>>(gsum, GG * 256 + 64);
  k_graphsum<<<GG * GCH, 256, 0, stream>>>(gid, feats, gsum, gcnt);
  k_graphdiv<<<GG, 256, 0, stream>>>(gsum, gcnt, out);
}

// Round 12
// 824.359 us; speedup vs baseline: 1.3927x; 1.3927x over previous
//
#include <hip/hip_runtime.h>

// RGCN: N=50000, E=600000, D=128, R=200, NB=4, ARD=32, L=2, G=50, NS=2000
// R16: full revert to R13 (830us, best verified), with ONE body-preserving
//      change: k_attn blocks 512 -> 1024 threads (16 waves, 256 edges, grid
//      2344, launch_bounds(1024,8)). Per-wave instruction stream is byte-
//      identical to R13 (allocator pins this kernel at 32 VGPR; R14/R15 showed
//      ANY extra live state spills -> body frozen). QW LDS-restage halves
//      (4688 -> 2344 stages, ~150 -> 75 MB L2 re-reads). LDS 32.8KB x 2 blk/CU,
//      32 waves/CU retained.
//   per layer l:
//     k_bigwT  : BigW^T split -> BThi/BTlo [896][128] bf16
//     k_qw     : A_w[:,256:320] split -> QWhi/QWlo [128][64] bf16
//     k_splitX : X -> Xhi/Xlo bf16x2 (NP=50048 padded)
//     k_mgemm  : 3-pass bf16x2 MFMA -> xw16 (Nx512 fp16), pstT (Nx256 fp16,
//                permuted), curr -> feats[:, l*128:+128] fp32
//     k_attn   : 256 CSR edges/block (16/wave), MFMA q-GEMM + MLP -> acf[p]
//     k_reduce : wave-per-tgt CSR reduction over fp16 xw, fp32 accum
// All accumulation fp32. ws ~174 MB.

#define NN 50000
#define NP 50048   // 391 * 128
#define EE 600000
#define DD 128
#define RR 200
#define NBASIS 4
#define LL 2
#define GG 50
#define NSRC 2000
#define GCH 8
#define SCANB 196  // ceil(NN/256)

typedef __attribute__((ext_vector_type(8))) short short8v;
typedef __attribute__((ext_vector_type(4))) float float4v;
typedef __attribute__((ext_vector_type(8))) _Float16 half8v;
typedef __attribute__((ext_vector_type(4))) _Float16 half4v;

__device__ __forceinline__ void f4a(const float4 v, float* a) {
  a[0] = v.x; a[1] = v.y; a[2] = v.z; a[3] = v.w;
}

__device__ __forceinline__ unsigned short f2bf(float v) {  // RNE bf16
  unsigned u = __float_as_uint(v);
  unsigned r = u + 0x7FFFu + ((u >> 16) & 1u);
  return (unsigned short)(r >> 16);
}
__device__ __forceinline__ float bf2f(unsigned short h) {
  return __uint_as_float(((unsigned)h) << 16);
}

// split 8 floats into hi/lo bf16 vectors
__device__ __forceinline__ void split8s(const float4 a, const float4 b,
                                        short8v* hi, short8v* lo) {
  float f[8];
  f4a(a, f); f4a(b, f + 4);
  short8v h, l;
#pragma unroll
  for (int j = 0; j < 8; ++j) {
    unsigned short hh = f2bf(f[j]);
    h[j] = (short)hh;
    l[j] = (short)f2bf(f[j] - bf2f(hh));
  }
  *hi = h; *lo = l;
}

// ---------------- BigW^T assembly + bf16x2 split: BT*[c*128 + i] ----------------
__global__ __launch_bounds__(256) void k_bigwT(const float* __restrict__ weights,
                                               const float* __restrict__ A_w,
                                               const float* __restrict__ self_loops,
                                               unsigned short* __restrict__ BThi,
                                               unsigned short* __restrict__ BTlo, int l) {
  int id = blockIdx.x * 256 + threadIdx.x;
  if (id >= 128 * 896) return;
  int i = id / 896, c = id % 896;  // i = K index, c = output col
  float v;
  if (c < 512) {            // xw: col b*128+o = weights[l][b][i][o]
    int b = c >> 7, o = c & 127;
    v = weights[((l * NBASIS + b) * DD + i) * DD + o];
  } else if (c < 640) {     // psrc
    int j = c - 512;
    v = A_w[(l * DD + j) * 320 + i];
  } else if (c < 768) {     // ptgt
    int j = c - 640;
    v = A_w[(l * DD + j) * 320 + 128 + i];
  } else {                  // curr
    int o = c - 768;
    v = self_loops[(l * DD + i) * DD + o];
  }
  unsigned short hi = f2bf(v);
  unsigned short lo = f2bf(v - bf2f(hi));
  BThi[c * 128 + i] = hi;
  BTlo[c * 128 + i] = lo;
}

// ---------------- q-GEMM weights: QW[j][k] = A_w[l][j][256+k], hi/lo bf16 ----------------
__global__ __launch_bounds__(256) void k_qw(const float* __restrict__ A_w,
                                            unsigned short* __restrict__ QWhi,
                                            unsigned short* __restrict__ QWlo, int l) {
  int id = blockIdx.x * 256 + threadIdx.x;
  if (id >= 128 * 64) return;
  int j = id >> 6, k = id & 63;
  float v = A_w[(l * DD + j) * 320 + 256 + k];
  unsigned short hi = f2bf(v);
  QWhi[id] = hi;
  QWlo[id] = f2bf(v - bf2f(hi));
}

// ---------------- X bf16x2 split (padded to NP rows) ----------------
__global__ __launch_bounds__(256) void k_splitX(const float* __restrict__ X, int xs,
                                                unsigned short* __restrict__ Xhi,
                                                unsigned short* __restrict__ Xlo) {
  int id = blockIdx.x * 256 + threadIdx.x;
  if (id >= NP * 128) return;
  int n = id >> 7, k = id & 127;
  float v = (n < NN) ? X[(size_t)n * xs + k] : 0.0f;
  unsigned short hi = f2bf(v);
  unsigned short lo = f2bf(v - bf2f(hi));
  Xhi[id] = hi;
  Xlo[id] = lo;
}

// ---------------- MFMA node GEMM: block 128m x 128n, wave 32m x 128n ----------------
// LDS: K-loop stages B (hi+lo) at stride 56 halves (2-way banks, 16B aligned);
// epilogue reuses LDS for C transpose -> coalesced half8/float4 row stores.
// pst (cb 4,5) written PERMUTED: col' = (lm>>2)*32 + nt*4 + (lm&3) so k_attn's
// per-lane ps/pt reads are contiguous 64B runs.
__global__ __launch_bounds__(256) void k_mgemm(const unsigned short* __restrict__ Xhi,
                                               const unsigned short* __restrict__ Xlo,
                                               const unsigned short* __restrict__ BThi,
                                               const unsigned short* __restrict__ BTlo,
                                               _Float16* __restrict__ xw16,
                                               _Float16* __restrict__ pst16,
                                               float* __restrict__ currdst) {
  __shared__ __align__(16) char smem[34816];
  unsigned short* sBhi = (unsigned short*)smem;        // [128][56] halves
  unsigned short* sBlo = sBhi + 128 * 56;
  _Float16* sC = (_Float16*)smem;                      // [128][136] halves (34816 B)
  float* sCf = (float*)smem;                           // [64][132] floats (33792 B)

  const int t = threadIdx.x;
  const int wv = t >> 6, lane = t & 63;
  const int lm = lane & 15, qd = lane >> 4;
  const int m0 = blockIdx.x * 128;
  const int cb = blockIdx.y;           // 0..6
  const int n0 = cb * 128;
  const int mw = m0 + wv * 32;         // wave's 32-row strip

  float4v acc[2][8];
#pragma unroll
  for (int mi = 0; mi < 2; ++mi)
#pragma unroll
    for (int nt = 0; nt < 8; ++nt) acc[mi][nt] = (float4v)(0.0f);

  const int sn = (t >> 2);             // staging row 0..63 (+64 on rep 1)
  const int skq = (t & 3) * 8;         // staging k-offset (halves)

  for (int kc = 0; kc < 128; kc += 32) {
    // stage B tile (128n x 32k, hi+lo) -> LDS
    short8v vh0 = *(const short8v*)(BThi + (size_t)(n0 + sn) * 128 + kc + skq);
    short8v vl0 = *(const short8v*)(BTlo + (size_t)(n0 + sn) * 128 + kc + skq);
    short8v vh1 = *(const short8v*)(BThi + (size_t)(n0 + 64 + sn) * 128 + kc + skq);
    short8v vl1 = *(const short8v*)(BTlo + (size_t)(n0 + 64 + sn) * 128 + kc + skq);
    if (kc) __syncthreads();           // prev tile's reads complete
    *(short8v*)&sBhi[sn * 56 + skq] = vh0;
    *(short8v*)&sBlo[sn * 56 + skq] = vl0;
    *(short8v*)&sBhi[(64 + sn) * 56 + skq] = vh1;
    *(short8v*)&sBlo[(64 + sn) * 56 + skq] = vl1;
    __syncthreads();
    // A fragments direct from global (L3-resident)
    short8v ah[2], al[2];
#pragma unroll
    for (int mi = 0; mi < 2; ++mi) {
      ah[mi] = *(const short8v*)(Xhi + (size_t)(mw + mi * 16 + lm) * 128 + kc + qd * 8);
      al[mi] = *(const short8v*)(Xlo + (size_t)(mw + mi * 16 + lm) * 128 + kc + qd * 8);
    }
#pragma unroll
    for (int nt = 0; nt < 8; ++nt) {
      short8v bh = *(const short8v*)&sBhi[(nt * 16 + lm) * 56 + qd * 8];
      short8v bl = *(const short8v*)&sBlo[(nt * 16 + lm) * 56 + qd * 8];
#pragma unroll
      for (int mi = 0; mi < 2; ++mi) {
        acc[mi][nt] = __builtin_amdgcn_mfma_f32_16x16x32_bf16(ah[mi], bh, acc[mi][nt], 0, 0, 0);
        acc[mi][nt] = __builtin_amdgcn_mfma_f32_16x16x32_bf16(ah[mi], bl, acc[mi][nt], 0, 0, 0);
        acc[mi][nt] = __builtin_amdgcn_mfma_f32_16x16x32_bf16(al[mi], bh, acc[mi][nt], 0, 0, 0);
      }
    }
  }

  // epilogue: C/D layout col = lane&15, row = qd*4 + reg  [m89/m91]
  if (cb < 6) {                        // fp16 tables, LDS transpose -> half8 row stores
    _Float16* dst16; int stride, off;
    if (cb < 4) { dst16 = xw16;  stride = 512; off = cb * 128; }
    else        { dst16 = pst16; stride = 256; off = (cb - 4) * 128; }
    __syncthreads();
#pragma unroll
    for (int mi = 0; mi < 2; ++mi)
#pragma unroll
      for (int nt = 0; nt < 8; ++nt)
#pragma unroll
        for (int r = 0; r < 4; ++r) {
          int col = (cb < 4) ? (nt * 16 + lm) : ((lm >> 2) * 32 + nt * 4 + (lm & 3));
          sC[(wv * 32 + mi * 16 + qd * 4 + r) * 136 + col] = (_Float16)acc[mi][nt][r];
        }
    __syncthreads();
#pragma unroll
    for (int rep = 0; rep < 8; ++rep) {
      int idx = rep * 256 + t;
      int row = idx >> 4, li = idx & 15;
      int m = m0 + row;
      if (m < NN)
        *(half8v*)&dst16[(size_t)m * stride + off + li * 8] =
            *(const half8v*)&sC[row * 136 + li * 8];
    }
  } else {                             // curr -> fp32 feats, two 64-row passes
#pragma unroll
    for (int pass = 0; pass < 2; ++pass) {
      __syncthreads();
      if ((wv >> 1) == pass) {
        int rbase = (wv & 1) * 32;
#pragma unroll
        for (int mi = 0; mi < 2; ++mi)
#pragma unroll
          for (int nt = 0; nt < 8; ++nt)
#pragma unroll
            for (int r = 0; r < 4; ++r)
              sCf[(rbase + mi * 16 + qd * 4 + r) * 132 + nt * 16 + lm] = acc[mi][nt][r];
      }
      __syncthreads();
#pragma unroll
      for (int rep = 0; rep < 8; ++rep) {
        int idx = rep * 256 + t;
        int lr = idx >> 5, li = idx & 31;
        int m = m0 + pass * 64 + lr;
        if (m < NN)
          *(float4*)&currdst[(size_t)m * 256 + li * 4] =
              *(const float4*)&sCf[lr * 132 + li * 4];
      }
    }
  }
}

// ---------------- Attention: 1024 threads, 256 CSR edges/block, QW in swizzled LDS --------
// Swapped MFMA: C[row=j][col=edge]. Lane (qd,lm) of wave wv (0..15) handles
// edge p = blk*256 + wv*16 + lm, holding j = nt*16 + qd*4 + r.
// Per-wave body byte-identical to R13 (frozen: 32-VGPR fit, no spills).
// nt in 4 groups of 2: acc live 8, ps/pt live 4; total live ~32.
__global__ __launch_bounds__(1024, 8) void k_attn(
    const int* __restrict__ srcs, const int* __restrict__ tgtc,
    const int* __restrict__ relc, const int* __restrict__ eord,
    const float* __restrict__ re, const float* __restrict__ tr,
    const unsigned short* __restrict__ QWhi, const unsigned short* __restrict__ QWlo,
    const float* __restrict__ A_b, const float* __restrict__ B_w,
    const float* __restrict__ B_b, const float* __restrict__ w_comps,
    const _Float16* __restrict__ pst16, float* __restrict__ acf, int l) {
  __shared__ __align__(16) unsigned short sQW[2 * 8192];   // hi | lo, 32768 B
  const int t = threadIdx.x;

  // stage QW -> LDS, XOR-swizzled: 16B chunk idx at byte idx*16 ^ ((idx>>3&7)<<4)
  {
    int ad = (t * 16) ^ (((t >> 3) & 7) << 4);
    *(short8v*)((char*)sQW + ad) = *(const short8v*)(QWhi + t * 8);
    *(short8v*)((char*)sQW + 16384 + ad) = *(const short8v*)(QWlo + t * 8);
  }

  const int wv = t >> 6, lane = t & 63;
  const int lm = lane & 15, qd = lane >> 4;
  const int p = blockIdx.x * 256 + wv * 16 + lm;  // this lane's CSR edge slot
  const int pc = min(p, EE - 1);                  // tail clamp (loads only)
  const int eid = eord[pc];
  const int src = srcs[pc], tgt = tgtc[pc];

  // E fragment: ecat[edge][k = kc + qd*8 .. +8), kc=0 -> re, kc=32 -> tr
  float4 r0 = *(const float4*)&re[(size_t)eid * 32 + qd * 8];
  float4 r1 = *(const float4*)&re[(size_t)eid * 32 + qd * 8 + 4];
  float4 t0 = *(const float4*)&tr[(size_t)eid * 32 + qd * 8];
  float4 t1 = *(const float4*)&tr[(size_t)eid * 32 + qd * 8 + 4];
  short8v eh0, el0, eh1, el1;
  split8s(r0, r1, &eh0, &el0);
  split8s(t0, t1, &eh1, &el1);

  __syncthreads();   // QW staged

  const int sw = (lm & 7) << 4;
  const _Float16* psp = pst16 + (size_t)src * 256 + qd * 32;
  const _Float16* ptp = pst16 + (size_t)tgt * 256 + 128 + qd * 32;
  float part = 0.0f;
#pragma unroll
  for (int g = 0; g < 4; ++g) {
    // group covers nt = 2g (ps[0..3]) and 2g+1 (ps[4..7])
    half8v ps = *(const half8v*)(psp + g * 8);
    half8v pt = *(const half8v*)(ptp + g * 8);
    float4v aa[2];
    aa[0] = (float4v)(0.0f);
    aa[1] = (float4v)(0.0f);
#pragma unroll
    for (int h = 0; h < 2; ++h) {
      const int nt = 2 * g + h;
      const int rowb = (nt * 16 + lm) * 128 + qd * 16;   // byte offset in hi half
      short8v wh0 = *(const short8v*)((char*)sQW + (rowb ^ sw));
      short8v wl0 = *(const short8v*)((char*)sQW + 16384 + (rowb ^ sw));
      // kc = 0 (re half), 3-pass hi/lo
      aa[h] = __builtin_amdgcn_mfma_f32_16x16x32_bf16(wh0, eh0, aa[h], 0, 0, 0);
      aa[h] = __builtin_amdgcn_mfma_f32_16x16x32_bf16(wl0, eh0, aa[h], 0, 0, 0);
      aa[h] = __builtin_amdgcn_mfma_f32_16x16x32_bf16(wh0, el0, aa[h], 0, 0, 0);
      short8v wh1 = *(const short8v*)((char*)sQW + ((rowb + 64) ^ sw));
      short8v wl1 = *(const short8v*)((char*)sQW + 16384 + ((rowb + 64) ^ sw));
      // kc = 32 (tr half)
      aa[h] = __builtin_amdgcn_mfma_f32_16x16x32_bf16(wh1, eh1, aa[h], 0, 0, 0);
      aa[h] = __builtin_amdgcn_mfma_f32_16x16x32_bf16(wl1, eh1, aa[h], 0, 0, 0);
      aa[h] = __builtin_amdgcn_mfma_f32_16x16x32_bf16(wh1, el1, aa[h], 0, 0, 0);
    }
    // MLP partial for this group (same per-nt term order as R13)
#pragma unroll
    for (int h = 0; h < 2; ++h) {
      const int nt = 2 * g + h;
      float4 ab = *(const float4*)&A_b[l * DD + nt * 16 + qd * 4];
      float4 bw = *(const float4*)&B_w[l * DD + nt * 16 + qd * 4];
      float abv[4], bwv[4];
      f4a(ab, abv); f4a(bw, bwv);
#pragma unroll
      for (int r = 0; r < 4; ++r) {
        float psf = (float)ps[h * 4 + r];
        float ptf = (float)pt[h * 4 + r];
        float hh = fmaxf(psf + ptf + aa[h][r] + abv[r], 0.0f);
        part += hh * bwv[r];
      }
    }
  }
  part += __shfl_xor(part, 16, 64);
  part += __shfl_xor(part, 32, 64);
  if (qd == 0 && p < EE) {
    const float a = 1.0f / (1.0f + expf(-(part + B_b[l])));
    const float4 cf = *(const float4*)&w_comps[(l * RR + relc[pc]) * 4];
    *(float4*)&acf[(size_t)p * 4] = make_float4(a * cf.x, a * cf.y, a * cf.z, a * cf.w);
  }
}

// ---------------- CSR build ----------------
__global__ __launch_bounds__(256) void k_zero_i(int* __restrict__ p, int n) {
  int id = blockIdx.x * 256 + threadIdx.x;
  if (id < n) p[id] = 0;
}
__global__ __launch_bounds__(256) void k_hist(const int* __restrict__ e_tgt,
                                              int* __restrict__ deg) {
  int e = blockIdx.x * 256 + threadIdx.x;
  if (e < EE) atomicAdd(&deg[e_tgt[e]], 1);
}

// 3-phase multi-block exclusive scan of deg -> rowptr/cursor
__global__ __launch_bounds__(256) void k_scan1(const int* __restrict__ deg,
                                               int* __restrict__ bsum) {
  __shared__ int red[4];
  const int t = threadIdx.x;
  int i = blockIdx.x * 256 + t;
  int v = (i < NN) ? deg[i] : 0;
#pragma unroll
  for (int m = 1; m < 64; m <<= 1) v += __shfl_xor(v, m, 64);
  if ((t & 63) == 0) red[t >> 6] = v;
  __syncthreads();
  if (t == 0) bsum[blockIdx.x] = red[0] + red[1] + red[2] + red[3];
}
__global__ __launch_bounds__(256) void k_scan2(const int* __restrict__ bsum,
                                               int* __restrict__ boff) {
  __shared__ int s[256];
  const int t = threadIdx.x;
  int v = (t < SCANB) ? bsum[t] : 0;
  s[t] = v;
  __syncthreads();
  for (int off = 1; off < 256; off <<= 1) {
    int u = (t >= off) ? s[t - off] : 0;
    __syncthreads();
    s[t] += u;
    __syncthreads();
  }
  if (t < SCANB) boff[t] = s[t] - v;   // exclusive
}
__global__ __launch_bounds__(256) void k_scan3(const int* __restrict__ deg,
                                               const int* __restrict__ boff,
                                               int* __restrict__ rowptr,
                                               int* __restrict__ cursor) {
  __shared__ int s[256];
  const int t = threadIdx.x;
  const int i = blockIdx.x * 256 + t;
  int v = (i < NN) ? deg[i] : 0;
  s[t] = v;
  __syncthreads();
  for (int off = 1; off < 256; off <<= 1) {
    int u = (t >= off) ? s[t - off] : 0;
    __syncthreads();
    s[t] += u;
    __syncthreads();
  }
  if (i < NN) {
    int ex = boff[blockIdx.x] + s[t] - v;
    rowptr[i] = ex;
    cursor[i] = ex;
  }
  if (i == NN - 1) rowptr[NN] = EE;
}

// fill: CSR-order srcs + inverse perm eord + CSR-order rel/tgt (layer-invariant)
__global__ __launch_bounds__(256) void k_fill(const int* __restrict__ e_tgt,
                                              const int* __restrict__ e_src,
                                              const int* __restrict__ rel,
                                              int* __restrict__ cursor,
                                              int* __restrict__ srcs,
                                              int* __restrict__ eord,
                                              int* __restrict__ relc,
                                              int* __restrict__ tgtc) {
  int e = blockIdx.x * 256 + threadIdx.x;
  if (e < EE) {
    int tg = e_tgt[e];
    int p = atomicAdd(&cursor[tg], 1);
    srcs[p] = e_src[e];
    eord[p] = e;
    relc[p] = rel[e];
    tgtc[p] = tg;
  }
}

// ---------------- CSR segmented reduction: one wave per tgt node ----------------
__global__ __launch_bounds__(256) void k_reduce(
    const int* __restrict__ rowptr, const int* __restrict__ srcs,
    const float* __restrict__ acf, const _Float16* __restrict__ xw16,
    float* __restrict__ feats, int l) {
  const int t = threadIdx.x;
  const int wave = t >> 6, lane = t & 63;
  const int n = blockIdx.x * 4 + wave;
  if (n >= NN) return;
  const int b = lane >> 4, li = lane & 15;
  float s[8] = {0, 0, 0, 0, 0, 0, 0, 0};
  const int lo = rowptr[n], hi = rowptr[n + 1];
  int snext = 0; float cnext = 0.0f;
  if (lo < hi) { snext = srcs[lo]; cnext = acf[lo * 4 + b]; }
  for (int i = lo; i < hi; ++i) {
    const int src = snext; const float cb_ = cnext;
    if (i + 1 < hi) { snext = srcs[i + 1]; cnext = acf[(i + 1) * 4 + b]; }
    half8v x = *(const half8v*)&xw16[(size_t)src * 512 + b * 128 + li * 8];
#pragma unroll
    for (int j = 0; j < 8; ++j) s[j] += cb_ * (float)x[j];
  }
#pragma unroll
  for (int j = 0; j < 8; ++j) {
    s[j] += __shfl_xor(s[j], 16, 64);
    s[j] += __shfl_xor(s[j], 32, 64);
  }
  if (lane < 16) {
    float* fp = &feats[(size_t)n * 256 + l * 128 + lane * 8];
    float4 c0 = *(const float4*)fp;
    float4 c1 = *(const float4*)(fp + 4);
    float4 o0 = make_float4(fmaxf(s[0] + c0.x, 0.f), fmaxf(s[1] + c0.y, 0.f),
                            fmaxf(s[2] + c0.z, 0.f), fmaxf(s[3] + c0.w, 0.f));
    float4 o1 = make_float4(fmaxf(s[4] + c1.x, 0.f), fmaxf(s[5] + c1.y, 0.f),
                            fmaxf(s[6] + c1.z, 0.f), fmaxf(s[7] + c1.w, 0.f));
    *(float4*)fp = o0;
    *(float4*)(fp + 4) = o1;
  }
}

// ---------------- readout ----------------
__global__ __launch_bounds__(256) void k_gather(const int* __restrict__ srcn,
                                                const int* __restrict__ tgtn,
                                                const float* __restrict__ feats,
                                                float* __restrict__ out) {
  int id = blockIdx.x * 256 + threadIdx.x;
  if (id >= 2 * NSRC * 256) return;
  int half = id / (NSRC * 256);
  int rem = id % (NSRC * 256);
  int s = rem >> 8, c = rem & 255;
  int n = half ? tgtn[s] : srcn[s];
  int base = GG * 256 + half * NSRC * 256;
  out[base + s * 256 + c] = feats[n * 256 + c];
}

__global__ __launch_bounds__(256) void k_zero(float* __restrict__ p, int n) {
  int id = blockIdx.x * 256 + threadIdx.x;
  if (id < n) p[id] = 0.0f;
}

__global__ __launch_bounds__(256) void k_graphsum(const int* __restrict__ gid,
                                                  const float* __restrict__ feats,
                                                  float* __restrict__ gsum,
                                                  float* __restrict__ gcnt) {
  const int g = blockIdx.x / GCH, ch = blockIdx.x % GCH;
  __shared__ int sb[2];
  if (threadIdx.x == 0) {
    int lo = 0, hi = NN;
    while (lo < hi) { int m = (lo + hi) >> 1; if (gid[m] < g) lo = m + 1; else hi = m; }
    sb[0] = lo;
    lo = 0; hi = NN;
    while (lo < hi) { int m = (lo + hi) >> 1; if (gid[m] < g + 1) lo = m + 1; else hi = m; }
    sb[1] = lo;
  }
  __syncthreads();
  const int lo = sb[0], hi = sb[1];
  if (ch == 0 && threadIdx.x == 0) gcnt[g] = (float)(hi - lo);
  const int cnt = hi - lo;
  const int per = (cnt + GCH - 1) / GCH;
  const int nlo = lo + ch * per, nhi = min(nlo + per, hi);
  float s = 0.0f;
  const int c = threadIdx.x;
  for (int n = nlo; n < nhi; ++n) s += feats[n * 256 + c];
  atomicAdd(&gsum[g * 256 + c], s);
}

__global__ __launch_bounds__(256) void k_graphdiv(const float* __restrict__ gsum,
                                                  const float* __restrict__ gcnt,
                                                  float* __restrict__ out) {
  int id = blockIdx.x * 256 + threadIdx.x;
  if (id >= GG * 256) return;
  out[id] = gsum[id] / gcnt[id >> 8];
}

extern "C" void kernel_launch(void* const* d_in, const int* in_sizes, int n_in,
                              void* d_out, int out_size, void* d_ws, size_t ws_size,
                              hipStream_t stream) {
  const float* node_feat  = (const float*)d_in[0];
  const int*   edge       = (const int*)d_in[1];
  const int*   rel        = (const int*)d_in[2];
  const float* re         = (const float*)d_in[3];
  const float* tr         = (const float*)d_in[4];
  const int*   srcn       = (const int*)d_in[5];
  const int*   tgtn       = (const int*)d_in[6];
  const int*   gid        = (const int*)d_in[7];
  const float* weights    = (const float*)d_in[8];
  const float* w_comps    = (const float*)d_in[9];
  const float* self_loops = (const float*)d_in[10];
  const float* A_w        = (const float*)d_in[11];
  const float* A_b        = (const float*)d_in[12];
  const float* B_w        = (const float*)d_in[13];
  const float* B_b        = (const float*)d_in[14];
  float* out = (float*)d_out;

  float* ws    = (float*)d_ws;
  float* feats = ws;                            // N*256 f32
  float* gsum  = feats + (size_t)NN * 256;      // GG*256
  float* gcnt  = gsum + GG * 256;               // 64
  float* acf   = gcnt + 64;                     // E*4
  _Float16* xw16  = (_Float16*)(acf + (size_t)EE * 4);  // N*512 fp16
  _Float16* pst16 = xw16 + (size_t)NN * 512;            // N*256 fp16 (permuted)
  unsigned short* Xhi  = (unsigned short*)(pst16 + (size_t)NN * 256);  // NP*128
  unsigned short* Xlo  = Xhi + (size_t)NP * 128;
  unsigned short* BThi = Xlo + (size_t)NP * 128;        // 896*128
  unsigned short* BTlo = BThi + 896 * 128;
  int* deg    = (int*)(BTlo + 896 * 128);       // N
  int* rowptr = deg + NN;                       // N+1
  int* cursor = rowptr + NN + 1;                // N
  int* srcs   = cursor + NN;                    // E
  int* eord   = srcs + EE;                      // E
  int* relc   = eord + EE;                      // E
  int* tgtc   = relc + EE;                      // E
  unsigned short* QWhi = (unsigned short*)(tgtc + EE);  // 128*64
  unsigned short* QWlo = QWhi + 128 * 64;
  int* bsum   = (int*)(QWlo + 128 * 64);        // SCANB
  int* boff   = bsum + 256;                     // SCANB
  // total ws ~174 MB

  const int* e_src = edge;
  const int* e_tgt = edge + EE;

  // CSR by tgt (layer-invariant)
  k_zero_i<<<(NN + 255) / 256, 256, 0, stream>>>(deg, NN);
  k_hist<<<(EE + 255) / 256, 256, 0, stream>>>(e_tgt, deg);
  k_scan1<<<SCANB, 256, 0, stream>>>(deg, bsum);
  k_scan2<<<1, 256, 0, stream>>>(bsum, boff);
  k_scan3<<<SCANB, 256, 0, stream>>>(deg, boff, rowptr, cursor);
  k_fill<<<(EE + 255) / 256, 256, 0, stream>>>(e_tgt, e_src, rel, cursor,
                                               srcs, eord, relc, tgtc);

  for (int l = 0; l < LL; ++l) {
    const float* X = (l == 0) ? node_feat : feats;  // layer1 input = feats[:, 0:128]
    int xs = (l == 0) ? 128 : 256;
    k_bigwT<<<(128 * 896 + 255) / 256, 256, 0, stream>>>(weights, A_w, self_loops,
                                                         BThi, BTlo, l);
    k_qw<<<(128 * 64 + 255) / 256, 256, 0, stream>>>(A_w, QWhi, QWlo, l);
    k_splitX<<<(NP * 128 + 255) / 256, 256, 0, stream>>>(X, xs, Xhi, Xlo);
    dim3 g1(NP / 128, 7);
    k_mgemm<<<g1, 256, 0, stream>>>(Xhi, Xlo, BThi, BTlo, xw16, pst16, feats + l * 128);
    k_attn<<<(EE + 255) / 256, 1024, 0, stream>>>(srcs, tgtc, relc, eord, re, tr,
                                                  QWhi, QWlo, A_b, B_w, B_b, w_comps,
                                                  pst16, acf, l);
    k_reduce<<<(NN + 3) / 4, 256, 0, stream>>>(rowptr, srcs, acf, xw16, feats, l);
  }
  k_gather<<<(2 * NSRC * 256 + 255) / 256, 256, 0, stream>>>(srcn, tgtn, feats, out);
  k_zero<<<(GG * 256 + 64 + 255) / 256, 256, 0, stream>>>(gsum, GG * 256 + 64);
  k_graphsum<<<GG * GCH, 256, 0, stream>>>(gid, feats, gsum, gcnt);
  k_graphdiv<<<GG, 256, 0, stream>>>(gsum, gcnt, out);
}